// Round 8
// baseline (232.703 us; speedup 1.0000x reference)
//
#include <hip/hip_runtime.h>
#include <math.h>

constexpr int NB = 1024;             // B (samples)
constexpr int NT = 8;                // T
constexpr int NV = 4;                // V
constexpr int ND = 8;                // D
constexpr int M = NB - 4;            // 1020 rows per task
constexpr int NTASK = NV * (NT - 1); // 28 tasks
constexpr int SEG = 16;              // k-steps per thread
constexpr int KB = 128;              // k-stripe width
constexpr int GPB = 32;              // G-groups (4 diags each) per block
constexpr int NSID = 36;             // stripe blocks per task

// ---- ws layout (bytes) ----
// 0        psi[1024] double
// 8192     accum double
// 8200     eps3[NTASK][1020][3] u32   (342720)
// 350920   counts[NTASK][1020] u32    (114240)
// 465168   packed[NTASK][2][1024][8] f32 (1835008)
constexpr size_t EPS3_OFF = 8200;
constexpr size_t PACKED_OFF = 465168;

// row-index swizzle: spreads stride-4 and stride-16 row accesses across banks
__device__ __forceinline__ int p2(int i) { return i ^ (((i >> 2) ^ (i >> 4)) & 3); }

__device__ __forceinline__ float cheb8(const float4& a0, const float4& a1,
                                       const float4& b0, const float4& b1) {
  float m0 = fmaxf(fabsf(a0.x - b0.x), fabsf(a0.y - b0.y));
  float m1 = fmaxf(fabsf(a0.z - b0.z), fabsf(a0.w - b0.w));
  float m2 = fmaxf(fabsf(a1.x - b1.x), fabsf(a1.y - b1.y));
  float m3 = fmaxf(fabsf(a1.z - b1.z), fabsf(a1.w - b1.w));
  return fmaxf(fmaxf(m0, m1), fmaxf(m2, m3));
}

// lock-free 3-smallest insert via cascaded atomicMin (LDS & global)
template <typename P>
__device__ __forceinline__ void cas3(P* a, unsigned v) {
  unsigned o = atomicMin(a + 0, v); v = v > o ? v : o;
  o = atomicMin(a + 1, v);          v = v > o ? v : o;
  atomicMin(a + 2, v);
}

__global__ void k_init(double* psi, unsigned* eps3, unsigned* counts, double* accum) {
  int gid = blockIdx.x * 256 + threadIdx.x;
  int stride = gridDim.x * 256;
  for (int j = gid; j < NTASK * 1020 * 3; j += stride) eps3[j] = 0xFFFFFFFFu;
  for (int j = gid; j < NTASK * 1020; j += stride) counts[j] = 0u;
  if (gid == 0) *accum = 0.0;
  if (gid >= 1 && gid < NB) {
    double x = (double)gid, acc = 0.0;
    while (x < 10.0) { acc -= 1.0 / x; x += 1.0; }
    double inv = 1.0 / x, i2 = inv * inv;
    double ps = log(x) - 0.5 * inv
              - i2 * (1.0 / 12.0 - i2 * (1.0 / 120.0 - i2 * (1.0 / 252.0)));
    psi[gid] = ps + acc;
  }
}

// gather x into packed [task][ser][row][8] so staging loads are stride-8
__global__ void k_prepack(const float* __restrict__ x, float* __restrict__ packed) {
  int idx = blockIdx.x * 256 + threadIdx.x;   // 28*2048 rows
  if (idx >= NTASK * 2048) return;
  int task = idx >> 11, r2 = idx & 2047, ser = r2 >> 10, row = r2 & 1023;
  int v = task / (NT - 1), ts = 1 + task % (NT - 1);
  int t = ser ? ts : 0;
  const float4* src = (const float4*)(x + ((size_t)(row * NT + t) * NV + v) * ND);
  float4* dst = (float4*)(packed + (size_t)idx * ND);
  dst[0] = src[0];
  dst[1] = src[1];
}

template <int PASS>
__global__ __launch_bounds__(256, 4)
void k_pass(const float* __restrict__ packed, unsigned* __restrict__ eps3,
            unsigned* __restrict__ counts) {
  // 32 KB static LDS -> 4-5 blocks/CU (vs 77.8 KB / 2 blocks in r5)
  __shared__ float4 TN[272], SN[272], TF[528], SF[528];  // near 136, far 264 rows
  __shared__ unsigned STATS[1600];  // p1: M3n[136][4]+M3f[264][4]; p2: eps/cnt pairs

  unsigned* M3n = STATS;
  unsigned* M3f = STATS + 544;
  float* EPn = (float*)STATS;           // [p*2], cnt at [p*2+1]
  float* EPf = (float*)(STATS + 272);
  unsigned* CTn = STATS;
  unsigned* CTf = STATS + 272;

  const int task = blockIdx.x;
  int gb = 0, ks = blockIdx.y;
  {
    const int nk[8] = {8, 7, 6, 5, 4, 3, 2, 1};
    while (ks >= nk[gb]) { ks -= nk[gb]; ++gb; }
  }
  const int NA0 = KB * ks;
  const int FB0 = KB * (ks + gb);
  const int tid = threadIdx.x;

  const float4* bT = (const float4*)(packed + (size_t)task * 2 * 1024 * ND);
  const float4* bS = bT + 2048;

  // ---- stage near (133 rows) + far (260 rows) windows, both series ----
  for (int i = tid; i < 786; i += 256) {
    const float4* src; float4* dst; int row;
    if (i < 266) {
      int ser = i >= 133 ? 1 : 0; int i2 = i - ser * 133;
      row = min(NA0 + i2, 1023); src = ser ? bS : bT;
      dst = (ser ? SN : TN) + p2(i2) * 2;
    } else {
      int j = i - 266; int ser = j >= 260 ? 1 : 0; int i2 = j - ser * 260;
      row = min(FB0 + i2, 1023); src = ser ? bS : bT;
      dst = (ser ? SF : TF) + p2(i2) * 2;
    }
    dst[0] = src[row * 2]; dst[1] = src[row * 2 + 1];
  }
  if constexpr (PASS == 1) {
    for (int i = tid; i < 1600; i += 256) STATS[i] = 0xFFFFFFFFu;
  } else {
    for (int i2 = tid; i2 < 136; i2 += 256) {
      int row = NA0 + i2;
      float e = 0.f;
      if (i2 <= 132 && row <= 1019) {
        const unsigned* g = eps3 + ((size_t)task * 1020 + row) * 3;
        unsigned m = g[0], m1 = g[1], m2 = g[2];
        m = m > m1 ? m : m1; m = m > m2 ? m : m2;
        e = __uint_as_float(m);
      }
      int p = p2(i2) * 2;
      EPn[p] = e; CTn[p + 1] = 0u;
    }
    for (int i2 = tid; i2 < 264; i2 += 256) {
      int row = FB0 + i2;
      float e = 0.f;
      if (i2 <= 259 && row <= 1019) {
        const unsigned* g = eps3 + ((size_t)task * 1020 + row) * 3;
        unsigned m = g[0], m1 = g[1], m2 = g[2];
        m = m > m1 ? m : m1; m = m > m2 ? m : m2;
        e = __uint_as_float(m);
      }
      int p = p2(i2) * 2;
      EPf[p] = e; CTf[p + 1] = 0u;
    }
  }
  __syncthreads();

  const int gg = tid >> 3;
  const int seg = tid & 7;
  const int G = GPB * gb + gg;
  const int dbase = 4 * G + 1;
  const int LG = 1019 - 4 * G;
  const int k0 = NA0 + SEG * seg;

  if (k0 < LG) {
    const int kend = min(k0 + SEG, LG);
    const int kb0 = k0 - 4;

    float uk3[4], pwA[4], pwB[4], pwC[4], vk2[4], qwA[4], qwB[4];
    #pragma unroll
    for (int g = 0; g < 4; ++g) {
      uk3[g] = pwA[g] = pwB[g] = pwC[g] = 0.f;
      vk2[g] = qwA[g] = qwB[g] = 0.f;
    }
    float4 ft[4][2], fs[4][2], nt[2][2], ns[2][2];
    float ef[4];        // pass2: rolling far-row eps
    unsigned thf[4];    // pass1: rolling far-row threshold (stale-high safe)
    float en = 0.f;
    unsigned thn = 0u;

    // clamped window accessors: clamped reads only ever feed masked pairs
    #define CLN(v) min(max((v), 0), 132)
    #define CLF(v) min(max((v), 0), 259)
    #define LD2(A, i2c, d) { int _p = p2(i2c) * 2; (d)[0] = A[_p]; (d)[1] = A[_p + 1]; }

    // prologue: windows for step kk = kb0
    #pragma unroll
    for (int g = 0; g < 4; ++g) {
      LD2(TF, CLF(k0 + dbase + g - FB0), ft[(1 + g) & 3]);
      LD2(SF, CLF(k0 - 1 + dbase + g - FB0), fs[g & 3]);
      int iE = p2(CLF(kb0 + dbase + g - FB0));
      if constexpr (PASS == 2) ef[(1 + g) & 3] = EPf[iE * 2];
      else thf[(1 + g) & 3] = M3f[iE * 4 + 2];
    }
    {
      LD2(TN, CLN(k0 - NA0), nt[0]);
      LD2(SN, CLN(k0 - 1 - NA0), ns[0]);
      int iE = p2(CLN(kb0 - NA0));
      if constexpr (PASS == 2) en = EPn[iE * 2];
      else thn = M3n[iE * 4 + 2];
    }

    #pragma unroll 1
    for (int it = 0; it < (SEG + 4) / 4; ++it) {
      #pragma unroll
      for (int phi = 0; phi < 4; ++phi) {
        const int kk = kb0 + it * 4 + phi;
        float u4[4], v3[4];
        u4[0] = cheb8(nt[phi & 1][0], nt[phi & 1][1],
                      ft[(phi + 1) & 3][0], ft[(phi + 1) & 3][1]);
        v3[0] = cheb8(ns[phi & 1][0], ns[phi & 1][1],
                      fs[phi & 3][0], fs[phi & 3][1]);
        // preloads for next step (overwrite just-consumed slots)
        LD2(TF, CLF(kk + dbase + 8 - FB0), ft[(phi + 1) & 3]);
        LD2(SF, CLF(kk + dbase + 7 - FB0), fs[phi & 3]);
        LD2(TN, CLN(kk + 5 - NA0), nt[(phi + 1) & 1]);
        LD2(SN, CLN(kk + 4 - NA0), ns[(phi + 1) & 1]);
        // next-step guard prefetch (stale-high is always safe)
        float efn = 0.f, enx = 0.f;
        unsigned thfn = 0u, thnx = 0u;
        {
          int iF = p2(CLF(kk + dbase + 4 - FB0));
          int iN = p2(CLN(kk + 1 - NA0));
          if constexpr (PASS == 2) { efn = EPf[iF * 2]; enx = EPn[iN * 2]; }
          else { thfn = M3f[iF * 4 + 2]; thnx = M3n[iN * 4 + 2]; }
        }
        #pragma unroll
        for (int g = 1; g < 4; ++g) {
          u4[g] = cheb8(nt[phi & 1][0], nt[phi & 1][1],
                        ft[(phi + 1 + g) & 3][0], ft[(phi + 1 + g) & 3][1]);
          v3[g] = cheb8(ns[phi & 1][0], ns[phi & 1][1],
                        fs[(phi + g) & 3][0], fs[(phi + g) & 3][1]);
        }
        const bool vb = (kk >= k0) & (kk < kend);
        const int iN2 = p2(CLN(kk - NA0));
        const float eN = en;
        unsigned thrN = thn;
        unsigned accN = 0;
        #pragma unroll
        for (int g = 0; g < 4; ++g) {
          float pw3 = fmaxf(uk3[g], u4[g]);
          float dC  = fmaxf(pwA[g], pwC[g]);
          float dAC = fmaxf(dC, u4[g]);
          float qw2 = fmaxf(vk2[g], v3[g]);
          float dB  = fmaxf(qwA[g], qw2);
          float dBC = fmaxf(dB, dC);
          float dJ  = fmaxf(dAC, dB);
          pwA[g] = pwB[g]; pwB[g] = pwC[g]; pwC[g] = pw3; uk3[g] = u4[g];
          qwA[g] = qwB[g]; qwB[g] = qw2; vk2[g] = v3[g];
          const bool mg = vb & (kk + dbase + g <= 1019);
          const int iF2 = p2(CLF(kk + dbase + g - FB0));
          if constexpr (PASS == 1) {
            if (mg) {
              unsigned dm = __float_as_uint(dJ);
              if (dm < thrN) {            // monotone threshold: safe to skip
                cas3(M3n + iN2 * 4, dm);
                thrN = M3n[iN2 * 4 + 2];
              }
              if (dm < thf[(phi + 1 + g) & 3]) cas3(M3f + iF2 * 4, dm);
            }
          } else {
            if (mg) {
              float eF = ef[(phi + 1 + g) & 3];
              unsigned pN = (unsigned)(dAC < eN) | ((unsigned)(dBC < eN) << 10)
                          | ((unsigned)(dC < eN) << 20);
              unsigned pF = (unsigned)(dAC < eF) | ((unsigned)(dBC < eF) << 10)
                          | ((unsigned)(dC < eF) << 20);
              accN += pN;
              if (pF) atomicAdd(&CTf[iF2 * 2 + 1], pF);
            }
          }
        }
        if constexpr (PASS == 2) {
          if (accN) atomicAdd(&CTn[iN2 * 2 + 1], accN);
          ef[(phi + 1) & 3] = efn;
          en = enx;
        } else {
          thf[(phi + 1) & 3] = thfn;
          thn = thnx;
        }
      }
    }
    #undef CLN
    #undef CLF
    #undef LD2
  }
  __syncthreads();

  // ---- merge windowed LDS stats to global (near rows [NA0,+128), far [FB0,+256)) ----
  if constexpr (PASS == 1) {
    for (int i = tid; i < 128 + 256; i += 256) {
      int isFar = i >= 128 ? 1 : 0;
      int i2 = i - isFar * 128;
      int row = (isFar ? FB0 : NA0) + i2;
      if (row <= 1019) {
        const unsigned* Lp = (isFar ? M3f : M3n) + p2(i2) * 4;
        unsigned* gph = eps3 + ((size_t)task * 1020 + row) * 3;
        unsigned thr = gph[2];   // stale-safe guard
        #pragma unroll
        for (int sl = 0; sl < 3; ++sl) {
          unsigned vv = Lp[sl];
          if (vv < thr) cas3(gph, vv);
        }
      }
    }
  } else {
    for (int i = tid; i < 128 + 256; i += 256) {
      int isFar = i >= 128 ? 1 : 0;
      int i2 = i - isFar * 128;
      int row = (isFar ? FB0 : NA0) + i2;
      if (row <= 1019) {
        unsigned vv = isFar ? CTf[p2(i2) * 2 + 1] : CTn[p2(i2) * 2 + 1];
        if (vv) atomicAdd(&counts[task * 1020 + row], vv);
      }
    }
  }
}

__global__ void k_sum(const unsigned* __restrict__ counts,
                      const double* __restrict__ psi, double* __restrict__ accum) {
  int gid = blockIdx.x * 256 + threadIdx.x;
  double term = 0.0;
  if (gid < NTASK * 1020) {
    unsigned p = counts[gid];
    int n0 = p & 1023, n1 = (p >> 10) & 1023, n2 = p >> 20;
    term = psi[n2 + 1] - psi[n0 + 1] - psi[n1 + 1];
  }
  #pragma unroll
  for (int off = 32; off > 0; off >>= 1) term += __shfl_down(term, off);
  if ((threadIdx.x & 63) == 0) atomicAdd(accum, term);
}

__global__ void k_fin(const double* __restrict__ psi, const double* __restrict__ accum,
                      float* __restrict__ out) {
  if (threadIdx.x == 0 && blockIdx.x == 0) {
    double total = (double)NTASK * psi[3] + accum[0] / (double)M;
    double scale = 0.1 / (double)(NT * NV * ND) / (double)NV;
    out[0] = (float)(scale * total);
  }
}

extern "C" void kernel_launch(void* const* d_in, const int* in_sizes, int n_in,
                              void* d_out, int out_size, void* d_ws, size_t ws_size,
                              hipStream_t stream) {
  const float* x = (const float*)d_in[0];
  double* psi = (double*)d_ws;
  double* accum = psi + 1024;
  unsigned* eps3 = (unsigned*)((char*)d_ws + EPS3_OFF);
  unsigned* counts = eps3 + NTASK * 1020 * 3;
  float* packed = (float*)((char*)d_ws + PACKED_OFF);
  float* out = (float*)d_out;

  hipLaunchKernelGGL(k_init, dim3(120), dim3(256), 0, stream, psi, eps3, counts, accum);
  hipLaunchKernelGGL(k_prepack, dim3((NTASK * 2048 + 255) / 256), dim3(256), 0, stream,
                     x, packed);
  hipLaunchKernelGGL(HIP_KERNEL_NAME(k_pass<1>), dim3(NTASK, NSID), dim3(256), 0,
                     stream, packed, eps3, counts);
  hipLaunchKernelGGL(HIP_KERNEL_NAME(k_pass<2>), dim3(NTASK, NSID), dim3(256), 0,
                     stream, packed, eps3, counts);
  hipLaunchKernelGGL(k_sum, dim3(112), dim3(256), 0, stream, counts, psi, accum);
  hipLaunchKernelGGL(k_fin, dim3(1), dim3(1), 0, stream, psi, accum, out);
}

// Round 9
// 131.934 us; speedup vs baseline: 1.7638x; 1.7638x over previous
//
#include <hip/hip_runtime.h>
#include <math.h>

constexpr int NB = 1024;             // B (samples)
constexpr int NT = 8;                // T
constexpr int NV = 4;                // V
constexpr int ND = 8;                // D
constexpr int M = NB - 4;            // 1020 rows per task
constexpr int NTASK = NV * (NT - 1); // 28 tasks
constexpr int SEG = 16;              // k-steps per thread
constexpr int KB = 128;              // k-stripe width
constexpr int GPB = 32;              // G-groups (4 diags each) per block
constexpr int NSID = 36;             // stripe blocks per task

// ---- ws layout (bytes) ----
// 0        psi[1024] double
// 8192     accum double
// 8200     eps3[NTASK][1020][3] u32   (342720)
// 350920   counts[NTASK][1020] u32    (114240)
// 465168   packed[NTASK][2][1024][8] f32 (1835008)
constexpr size_t EPS3_OFF = 8200;
constexpr size_t PACKED_OFF = 465168;

// bank swizzle at float4 granularity: injects row bits into bank-cluster bits.
// Bijective (XOR of low-3 with a function of higher bits).
__device__ __forceinline__ int swz(int f4) {
  return f4 ^ (((f4 >> 3) ^ (f4 >> 6)) & 7);
}

__device__ __forceinline__ float cheb8(const float4& a0, const float4& a1,
                                       const float4& b0, const float4& b1) {
  float m0 = fmaxf(fabsf(a0.x - b0.x), fabsf(a0.y - b0.y));
  float m1 = fmaxf(fabsf(a0.z - b0.z), fabsf(a0.w - b0.w));
  float m2 = fmaxf(fabsf(a1.x - b1.x), fabsf(a1.y - b1.y));
  float m3 = fmaxf(fabsf(a1.z - b1.z), fabsf(a1.w - b1.w));
  return fmaxf(fmaxf(m0, m1), fmaxf(m2, m3));
}

// lock-free 3-smallest insert via cascaded atomicMin (LDS & global)
template <typename P>
__device__ __forceinline__ void cas3(P* a, unsigned v) {
  unsigned o = atomicMin(a + 0, v); v = v > o ? v : o;
  o = atomicMin(a + 1, v);          v = v > o ? v : o;
  atomicMin(a + 2, v);
}

__global__ void k_init(double* psi, unsigned* eps3, unsigned* counts, double* accum) {
  int gid = blockIdx.x * 256 + threadIdx.x;
  int stride = gridDim.x * 256;
  for (int j = gid; j < NTASK * 1020 * 3; j += stride) eps3[j] = 0xFFFFFFFFu;
  for (int j = gid; j < NTASK * 1020; j += stride) counts[j] = 0u;
  if (gid == 0) *accum = 0.0;
  if (gid >= 1 && gid < NB) {
    double x = (double)gid, acc = 0.0;
    while (x < 10.0) { acc -= 1.0 / x; x += 1.0; }
    double inv = 1.0 / x, i2 = inv * inv;
    double ps = log(x) - 0.5 * inv
              - i2 * (1.0 / 12.0 - i2 * (1.0 / 120.0 - i2 * (1.0 / 252.0)));
    psi[gid] = ps + acc;
  }
}

// gather x into packed [task][ser][row][8] so staging loads are stride-8
__global__ void k_prepack(const float* __restrict__ x, float* __restrict__ packed) {
  int idx = blockIdx.x * 256 + threadIdx.x;   // 28*2048 rows
  if (idx >= NTASK * 2048) return;
  int task = idx >> 11, r2 = idx & 2047, ser = r2 >> 10, row = r2 & 1023;
  int v = task / (NT - 1), ts = 1 + task % (NT - 1);
  int t = ser ? ts : 0;
  const float4* src = (const float4*)(x + ((size_t)(row * NT + t) * NV + v) * ND);
  float4* dst = (float4*)(packed + (size_t)idx * ND);
  dst[0] = src[0];
  dst[1] = src[1];
}

// NOTE: no min-waves clamp — this loop needs ~80-100 VGPR; forcing 4 waves/EU
// clamps to 64 and spills (r4/r6/r8: 175-276 MB scratch). LDS 33.6 KB caps
// residency at 4 blocks/CU anyway, which the 1008-block grid exactly supplies.
template <int PASS>
__global__ __launch_bounds__(256, 2)
void k_pass(const float* __restrict__ packed, unsigned* __restrict__ eps3,
            unsigned* __restrict__ counts) {
  __shared__ float4 TN[272], SN[272], TF[528], SF[528];  // near 133, far 260 rows
  __shared__ unsigned STATS[2000];  // stride-5/row: p1 M3[.]{0..2}; p2 EP[.]{0},CT[.]{1}

  unsigned* M3n = STATS;            // near rows: idx*5 + slot
  unsigned* M3f = STATS + 680;      // far rows:  idx*5 + slot
  float* EPn = (float*)STATS;
  float* EPf = (float*)(STATS + 680);
  unsigned* CTn = STATS;
  unsigned* CTf = STATS + 680;

  const int task = blockIdx.x;
  int gb = 0, ks = blockIdx.y;
  {
    const int nk[8] = {8, 7, 6, 5, 4, 3, 2, 1};
    while (ks >= nk[gb]) { ks -= nk[gb]; ++gb; }
  }
  const int NA0 = KB * ks;
  const int FB0 = KB * (ks + gb);
  const int tid = threadIdx.x;

  const float4* bT = (const float4*)(packed + (size_t)task * 2 * 1024 * ND);
  const float4* bS = bT + 2048;

  // ---- stage near (133 rows) + far (260 rows) windows, both series ----
  for (int i = tid; i < 786; i += 256) {
    const float4* src; float4* dst; int row, i2;
    if (i < 266) {
      int ser = i >= 133 ? 1 : 0; i2 = i - ser * 133;
      row = min(NA0 + i2, 1023); src = ser ? bS : bT;
      dst = ser ? SN : TN;
    } else {
      int j = i - 266; int ser = j >= 260 ? 1 : 0; i2 = j - ser * 260;
      row = min(FB0 + i2, 1023); src = ser ? bS : bT;
      dst = ser ? SF : TF;
    }
    dst[swz(i2 * 2)] = src[row * 2];
    dst[swz(i2 * 2 + 1)] = src[row * 2 + 1];
  }
  if constexpr (PASS == 1) {
    for (int i = tid; i < 2000; i += 256) STATS[i] = 0xFFFFFFFFu;
  } else {
    for (int i2 = tid; i2 < 136; i2 += 256) {
      int row = NA0 + i2;
      float e = 0.f;
      if (i2 <= 132 && row <= 1019) {
        const unsigned* g = eps3 + ((size_t)task * 1020 + row) * 3;
        unsigned m = g[0], m1 = g[1], m2 = g[2];
        m = m > m1 ? m : m1; m = m > m2 ? m : m2;
        e = __uint_as_float(m);
      }
      EPn[i2 * 5] = e; CTn[i2 * 5 + 1] = 0u;
    }
    for (int i2 = tid; i2 < 264; i2 += 256) {
      int row = FB0 + i2;
      float e = 0.f;
      if (i2 <= 259 && row <= 1019) {
        const unsigned* g = eps3 + ((size_t)task * 1020 + row) * 3;
        unsigned m = g[0], m1 = g[1], m2 = g[2];
        m = m > m1 ? m : m1; m = m > m2 ? m : m2;
        e = __uint_as_float(m);
      }
      EPf[i2 * 5] = e; CTf[i2 * 5 + 1] = 0u;
    }
  }
  __syncthreads();

  const int gg = tid >> 3;
  const int seg = tid & 7;
  const int G = GPB * gb + gg;
  const int dbase = 4 * G + 1;
  const int LG = 1019 - 4 * G;
  const int k0 = NA0 + SEG * seg;

  if (k0 < LG) {
    const int kend = min(k0 + SEG, LG);
    const int kb0 = k0 - 4;

    float uk3[4], pwA[4], pwB[4], pwC[4], vk2[4], qwA[4], qwB[4];
    #pragma unroll
    for (int g = 0; g < 4; ++g) {
      uk3[g] = pwA[g] = pwB[g] = pwC[g] = 0.f;
      vk2[g] = qwA[g] = qwB[g] = 0.f;
    }
    float4 ft[4][2], fs[4][2], nt[2][2], ns[2][2];
    float ef[4];        // pass2: rolling far-row eps
    unsigned thf[4];    // pass1: rolling far-row threshold (stale-high safe)
    float en = 0.f;
    unsigned thn = 0u;

    // clamped window accessors: clamped reads only ever feed masked pairs
    #define CLN(v) min(max((v), 0), 132)
    #define CLF(v) min(max((v), 0), 259)
    #define LD2(A, i2c, d) { int _b = (i2c) * 2; (d)[0] = A[swz(_b)]; (d)[1] = A[swz(_b + 1)]; }

    // prologue: windows for step kk = kb0
    #pragma unroll
    for (int g = 0; g < 4; ++g) {
      LD2(TF, CLF(k0 + dbase + g - FB0), ft[(1 + g) & 3]);
      LD2(SF, CLF(k0 - 1 + dbase + g - FB0), fs[g & 3]);
      int iE = CLF(kb0 + dbase + g - FB0);
      if constexpr (PASS == 2) ef[(1 + g) & 3] = EPf[iE * 5];
      else thf[(1 + g) & 3] = M3f[iE * 5 + 2];
    }
    {
      LD2(TN, CLN(k0 - NA0), nt[0]);
      LD2(SN, CLN(k0 - 1 - NA0), ns[0]);
      int iE = CLN(kb0 - NA0);
      if constexpr (PASS == 2) en = EPn[iE * 5];
      else thn = M3n[iE * 5 + 2];
    }

    #pragma unroll 1
    for (int it = 0; it < (SEG + 4) / 4; ++it) {
      #pragma unroll
      for (int phi = 0; phi < 4; ++phi) {
        const int kk = kb0 + it * 4 + phi;
        float u4[4], v3[4];
        u4[0] = cheb8(nt[phi & 1][0], nt[phi & 1][1],
                      ft[(phi + 1) & 3][0], ft[(phi + 1) & 3][1]);
        v3[0] = cheb8(ns[phi & 1][0], ns[phi & 1][1],
                      fs[phi & 3][0], fs[phi & 3][1]);
        // preloads for next step (overwrite just-consumed slots)
        LD2(TF, CLF(kk + dbase + 8 - FB0), ft[(phi + 1) & 3]);
        LD2(SF, CLF(kk + dbase + 7 - FB0), fs[phi & 3]);
        LD2(TN, CLN(kk + 5 - NA0), nt[(phi + 1) & 1]);
        LD2(SN, CLN(kk + 4 - NA0), ns[(phi + 1) & 1]);
        // next-step guard prefetch (stale-high is always safe)
        float efn = 0.f, enx = 0.f;
        unsigned thfn = 0u, thnx = 0u;
        {
          int iF = CLF(kk + dbase + 4 - FB0);
          int iN = CLN(kk + 1 - NA0);
          if constexpr (PASS == 2) { efn = EPf[iF * 5]; enx = EPn[iN * 5]; }
          else { thfn = M3f[iF * 5 + 2]; thnx = M3n[iN * 5 + 2]; }
        }
        #pragma unroll
        for (int g = 1; g < 4; ++g) {
          u4[g] = cheb8(nt[phi & 1][0], nt[phi & 1][1],
                        ft[(phi + 1 + g) & 3][0], ft[(phi + 1 + g) & 3][1]);
          v3[g] = cheb8(ns[phi & 1][0], ns[phi & 1][1],
                        fs[(phi + g) & 3][0], fs[(phi + g) & 3][1]);
        }
        const bool vb = (kk >= k0) & (kk < kend);
        const int iN2 = CLN(kk - NA0);
        const float eN = en;
        unsigned thrN = thn;
        unsigned accN = 0;
        #pragma unroll
        for (int g = 0; g < 4; ++g) {
          float pw3 = fmaxf(uk3[g], u4[g]);
          float dC  = fmaxf(pwA[g], pwC[g]);
          float dAC = fmaxf(dC, u4[g]);
          float qw2 = fmaxf(vk2[g], v3[g]);
          float dB  = fmaxf(qwA[g], qw2);
          float dBC = fmaxf(dB, dC);
          float dJ  = fmaxf(dAC, dB);
          pwA[g] = pwB[g]; pwB[g] = pwC[g]; pwC[g] = pw3; uk3[g] = u4[g];
          qwA[g] = qwB[g]; qwB[g] = qw2; vk2[g] = v3[g];
          const bool mg = vb & (kk + dbase + g <= 1019);
          const int iF2 = CLF(kk + dbase + g - FB0);
          if constexpr (PASS == 1) {
            if (mg) {
              unsigned dm = __float_as_uint(dJ);
              if (dm < thrN) {            // monotone threshold: safe to skip
                cas3(M3n + iN2 * 5, dm);
                thrN = M3n[iN2 * 5 + 2];
              }
              if (dm < thf[(phi + 1 + g) & 3]) cas3(M3f + iF2 * 5, dm);
            }
          } else {
            if (mg) {
              float eF = ef[(phi + 1 + g) & 3];
              unsigned pN = (unsigned)(dAC < eN) | ((unsigned)(dBC < eN) << 10)
                          | ((unsigned)(dC < eN) << 20);
              unsigned pF = (unsigned)(dAC < eF) | ((unsigned)(dBC < eF) << 10)
                          | ((unsigned)(dC < eF) << 20);
              accN += pN;
              if (pF) atomicAdd(&CTf[iF2 * 5 + 1], pF);
            }
          }
        }
        if constexpr (PASS == 2) {
          if (accN) atomicAdd(&CTn[iN2 * 5 + 1], accN);
          ef[(phi + 1) & 3] = efn;
          en = enx;
        } else {
          thf[(phi + 1) & 3] = thfn;
          thn = thnx;
        }
      }
    }
    #undef CLN
    #undef CLF
    #undef LD2
  }
  __syncthreads();

  // ---- merge windowed LDS stats to global (near rows [NA0,+128), far [FB0,+256)) ----
  if constexpr (PASS == 1) {
    for (int i = tid; i < 128 + 256; i += 256) {
      int isFar = i >= 128 ? 1 : 0;
      int i2 = i - isFar * 128;
      int row = (isFar ? FB0 : NA0) + i2;
      if (row <= 1019) {
        const unsigned* Lp = (isFar ? M3f : M3n) + i2 * 5;
        unsigned* gph = eps3 + ((size_t)task * 1020 + row) * 3;
        unsigned thr = gph[2];   // stale-safe guard
        #pragma unroll
        for (int sl = 0; sl < 3; ++sl) {
          unsigned vv = Lp[sl];
          if (vv < thr) cas3(gph, vv);
        }
      }
    }
  } else {
    for (int i = tid; i < 128 + 256; i += 256) {
      int isFar = i >= 128 ? 1 : 0;
      int i2 = i - isFar * 128;
      int row = (isFar ? FB0 : NA0) + i2;
      if (row <= 1019) {
        unsigned vv = isFar ? CTf[i2 * 5 + 1] : CTn[i2 * 5 + 1];
        if (vv) atomicAdd(&counts[task * 1020 + row], vv);
      }
    }
  }
}

__global__ void k_sum(const unsigned* __restrict__ counts,
                      const double* __restrict__ psi, double* __restrict__ accum) {
  int gid = blockIdx.x * 256 + threadIdx.x;
  double term = 0.0;
  if (gid < NTASK * 1020) {
    unsigned p = counts[gid];
    int n0 = p & 1023, n1 = (p >> 10) & 1023, n2 = p >> 20;
    term = psi[n2 + 1] - psi[n0 + 1] - psi[n1 + 1];
  }
  #pragma unroll
  for (int off = 32; off > 0; off >>= 1) term += __shfl_down(term, off);
  if ((threadIdx.x & 63) == 0) atomicAdd(accum, term);
}

__global__ void k_fin(const double* __restrict__ psi, const double* __restrict__ accum,
                      float* __restrict__ out) {
  if (threadIdx.x == 0 && blockIdx.x == 0) {
    double total = (double)NTASK * psi[3] + accum[0] / (double)M;
    double scale = 0.1 / (double)(NT * NV * ND) / (double)NV;
    out[0] = (float)(scale * total);
  }
}

extern "C" void kernel_launch(void* const* d_in, const int* in_sizes, int n_in,
                              void* d_out, int out_size, void* d_ws, size_t ws_size,
                              hipStream_t stream) {
  const float* x = (const float*)d_in[0];
  double* psi = (double*)d_ws;
  double* accum = psi + 1024;
  unsigned* eps3 = (unsigned*)((char*)d_ws + EPS3_OFF);
  unsigned* counts = eps3 + NTASK * 1020 * 3;
  float* packed = (float*)((char*)d_ws + PACKED_OFF);
  float* out = (float*)d_out;

  hipLaunchKernelGGL(k_init, dim3(120), dim3(256), 0, stream, psi, eps3, counts, accum);
  hipLaunchKernelGGL(k_prepack, dim3((NTASK * 2048 + 255) / 256), dim3(256), 0, stream,
                     x, packed);
  hipLaunchKernelGGL(HIP_KERNEL_NAME(k_pass<1>), dim3(NTASK, NSID), dim3(256), 0,
                     stream, packed, eps3, counts);
  hipLaunchKernelGGL(HIP_KERNEL_NAME(k_pass<2>), dim3(NTASK, NSID), dim3(256), 0,
                     stream, packed, eps3, counts);
  hipLaunchKernelGGL(k_sum, dim3(112), dim3(256), 0, stream, counts, psi, accum);
  hipLaunchKernelGGL(k_fin, dim3(1), dim3(1), 0, stream, psi, accum, out);
}